// Round 4
// baseline (239.581 us; speedup 1.0000x reference)
//
#include <hip/hip_runtime.h>
#include <stdint.h>

#define D_EMB 128
#define HIDDEN 64
#define PACK_SCALE 1024.0f
#define INV_PACK (1.0f/1024.0f)

__device__ __forceinline__ uint32_t rotl32(uint32_t x, int r) {
    return (x << r) | (x >> (32 - r));
}

// Bit-exact JAX threefry2x32, PARTITIONABLE path (default since jax 0.4.36).
// key = jax.random.key(42) -> (k1,k2) = (0,42); draw = final_x0 ^ final_x1 of
// counts (0, e).
__device__ __forceinline__ uint32_t jax_threefry_bits_part(uint32_t e) {
    const uint32_t ks0 = 0u;
    const uint32_t ks1 = 42u;
    const uint32_t ks2 = 0x1BD11BDAu ^ 0u ^ 42u;
    uint32_t x0 = 0u + ks0;
    uint32_t x1 = e + ks1;
#define TF_R(r) { x0 += x1; x1 = rotl32(x1, (r)); x1 ^= x0; }
    TF_R(13) TF_R(15) TF_R(26) TF_R(6)
    x0 += ks1; x1 += ks2 + 1u;
    TF_R(17) TF_R(29) TF_R(16) TF_R(24)
    x0 += ks2; x1 += ks0 + 2u;
    TF_R(13) TF_R(15) TF_R(26) TF_R(6)
    x0 += ks0; x1 += ks1 + 3u;
    TF_R(17) TF_R(29) TF_R(16) TF_R(24)
    x0 += ks1; x1 += ks2 + 4u;
    TF_R(13) TF_R(15) TF_R(26) TF_R(6)
    x0 += ks2; x1 += ks0 + 5u;
#undef TF_R
    return x0 ^ x1;
}

// Per-edge MLP logit -> concrete-sample gate value v in (0,1).
__device__ __forceinline__ float edge_gate_value(
    const float* __restrict__ Pcat, const float* __restrict__ w2s, float b2v,
    int c, int r, int e) {
    const float4* p1 = (const float4*)(Pcat + (size_t)c * (2 * HIDDEN));
    const float4* p2 = (const float4*)(Pcat + (size_t)r * (2 * HIDDEN) + HIDDEN);
    const float4* w4 = (const float4*)w2s;
    float la = b2v;
#pragma unroll
    for (int k = 0; k < HIDDEN / 4; k++) {
        float4 a = p1[k];
        float4 b = p2[k];
        float4 w = w4[k];
        la += fmaxf(a.x + b.x, 0.0f) * w.x + fmaxf(a.y + b.y, 0.0f) * w.y +
              fmaxf(a.z + b.z, 0.0f) * w.z + fmaxf(a.w + b.w, 0.0f) * w.w;
    }
    uint32_t bits = jax_threefry_bits_part((uint32_t)e);
    float u = __uint_as_float((bits >> 9) | 0x3f800000u) - 1.0f;
    // sigmoid(log(u) - log1p(-u) + la) == u / (u + (1-u)*exp(-la))
    return u / (u + (1.0f - u) * __expf(-la));
}

// Kernel 1: per-node projections. Pcat[n][0:64] = embed[n] @ W1[0:128] + b1
//           Pcat[n][64:128] = embed[n] @ W1[128:256]
__global__ __launch_bounds__(128) void node_proj_kernel(
    const float* __restrict__ embed, const float* __restrict__ W1,
    const float* __restrict__ b1, float* __restrict__ Pcat) {
    __shared__ float e_lds[D_EMB];
    int n = blockIdx.x;
    int t = threadIdx.x;             // 0..127
    e_lds[t] = embed[(size_t)n * D_EMB + t];
    __syncthreads();
    int half = t >> 6;               // 0 -> P1 (col side), 1 -> P2 (row side)
    int k = t & 63;
    const float* w = W1 + (size_t)half * D_EMB * HIDDEN + k;
    float acc = (half == 0) ? b1[k] : 0.0f;
#pragma unroll 16
    for (int d = 0; d < D_EMB; d++) {
        acc += e_lds[d] * w[(size_t)d * HIDDEN];
    }
    Pcat[(size_t)n * (2 * HIDDEN) + t] = acc;
}

// ---------------- hash-table path (L2-resident accumulator) ----------------
// Entry i: tab[2i] = key+1 (0 = empty), tab[2i+1] = float bits of 1024*cnt+sum.

__global__ __launch_bounds__(256) void scatter_hash_kernel(
    const int* __restrict__ ei, const float* __restrict__ Pcat,
    const float* __restrict__ W2, const float* __restrict__ b2,
    uint32_t* __restrict__ tab, int E, int N, int log_sz) {
    __shared__ float w2s[HIDDEN];
    if (threadIdx.x < HIDDEN) w2s[threadIdx.x] = W2[threadIdx.x];
    __syncthreads();
    int e = blockIdx.x * blockDim.x + threadIdx.x;
    if (e >= E) return;
    int c = ei[e];
    int r = ei[E + e];
    if ((unsigned)c >= (unsigned)N || (unsigned)r >= (unsigned)N) return;

    float v = edge_gate_value(Pcat, w2s, b2[0], c, r, e);

    uint32_t key = (uint32_t)c * (uint32_t)N + (uint32_t)r;
    uint32_t mask = (1u << log_sz) - 1u;
    uint32_t h = (key * 2654435761u) >> (32 - log_sz);
    for (;;) {
        uint32_t prev = atomicCAS(&tab[2 * h], 0u, key + 1u);
        if (prev == 0u || prev == key + 1u) break;
        h = (h + 1u) & mask;
    }
    atomicAdd((float*)&tab[2 * h + 1], PACK_SCALE + v);
}

__device__ __forceinline__ float hash_lookup(
    const uint32_t* __restrict__ tab, uint32_t key, int log_sz) {
    uint32_t mask = (1u << log_sz) - 1u;
    uint32_t h = (key * 2654435761u) >> (32 - log_sz);
    for (;;) {
        uint2 ent = ((const uint2*)tab)[h];
        if (ent.x == key + 1u) return __uint_as_float(ent.y);
        if (ent.x == 0u) return 0.0f;
        h = (h + 1u) & mask;
    }
}

// Kernel 3 (hash path): per-edge lookup both directions, write final value
// directly into the zeroed dense out. Idempotent across duplicates.
__global__ __launch_bounds__(256) void finalize_hash_kernel(
    const int* __restrict__ ei, const uint32_t* __restrict__ tab,
    float* __restrict__ out, int E, int N, int log_sz) {
    int e = blockIdx.x * blockDim.x + threadIdx.x;
    if (e >= E) return;
    int c = ei[e];
    int r = ei[E + e];
    if ((unsigned)c >= (unsigned)N || (unsigned)r >= (unsigned)N) return;
    uint32_t kf = (uint32_t)c * (uint32_t)N + (uint32_t)r;
    uint32_t kb = (uint32_t)r * (uint32_t)N + (uint32_t)c;
    float a = hash_lookup(tab, kf, log_sz);
    float b = hash_lookup(tab, kb, log_sz);
    float cnt_a = truncf(a * INV_PACK);
    float s_a = a - PACK_SCALE * cnt_a;
    float cnt_b = truncf(b * INV_PACK);
    float s_b = b - PACK_SCALE * cnt_b;
    out[(size_t)c * N + r] = cnt_a * 0.5f * (s_a + s_b);
}

// ---------------- dense fallback path (ws too small for hash) ----------------

__global__ __launch_bounds__(256) void edge_scatter_kernel(
    const int* __restrict__ ei, const float* __restrict__ Pcat,
    const float* __restrict__ W2, const float* __restrict__ b2,
    float* __restrict__ out, int E, int N) {
    __shared__ float w2s[HIDDEN];
    if (threadIdx.x < HIDDEN) w2s[threadIdx.x] = W2[threadIdx.x];
    __syncthreads();
    int e = blockIdx.x * blockDim.x + threadIdx.x;
    if (e >= E) return;
    int c = ei[e];
    int r = ei[E + e];
    if ((unsigned)c >= (unsigned)N || (unsigned)r >= (unsigned)N) return;
    float v = edge_gate_value(Pcat, w2s, b2[0], c, r, e);
    atomicAdd(out + (size_t)c * N + r, PACK_SCALE + v);
}

__global__ __launch_bounds__(256) void edge_read_kernel(
    const int* __restrict__ ei, const float* __restrict__ out,
    float* __restrict__ vals, int E, int N) {
    int e = blockIdx.x * blockDim.x + threadIdx.x;
    if (e >= E) return;
    int c = ei[e];
    int r = ei[E + e];
    if ((unsigned)c >= (unsigned)N || (unsigned)r >= (unsigned)N) return;
    float a = out[(size_t)c * N + r];
    float b = out[(size_t)r * N + c];
    float cnt_a = truncf(a * INV_PACK);
    float s_a = a - PACK_SCALE * cnt_a;
    float cnt_b = truncf(b * INV_PACK);
    float s_b = b - PACK_SCALE * cnt_b;
    vals[e] = cnt_a * 0.5f * (s_a + s_b);
}

__global__ __launch_bounds__(256) void edge_write_kernel(
    const int* __restrict__ ei, const float* __restrict__ vals,
    float* __restrict__ out, int E, int N) {
    int e = blockIdx.x * blockDim.x + threadIdx.x;
    if (e >= E) return;
    int c = ei[e];
    int r = ei[E + e];
    if ((unsigned)c >= (unsigned)N || (unsigned)r >= (unsigned)N) return;
    out[(size_t)c * N + r] = vals[e];
}

extern "C" void kernel_launch(void* const* d_in, const int* in_sizes, int n_in,
                              void* d_out, int out_size, void* d_ws, size_t ws_size,
                              hipStream_t stream) {
    const float* embed = (const float*)d_in[0];
    const int*   ei    = (const int*)d_in[1];
    const float* W1    = (const float*)d_in[2];
    const float* b1    = (const float*)d_in[3];
    const float* W2    = (const float*)d_in[4];
    const float* b2    = (const float*)d_in[5];
    float* out = (float*)d_out;

    const int N = in_sizes[0] / D_EMB;      // 10000
    const int E = in_sizes[1] / 2;          // 640000

    float* Pcat = (float*)d_ws;             // N*128 floats = 5.12 MB
    size_t pcat_bytes = ((size_t)N * 2 * HIDDEN * sizeof(float) + 255) & ~(size_t)255;
    size_t avail = (ws_size > pcat_bytes) ? (ws_size - pcat_bytes) : 0;

    // Largest 2^L entries (8B each) fitting in remaining ws, capped at 2^22.
    // Need >= 2^20 entries so load factor stays <= ~0.61 for 640k keys.
    int log_sz = 0;
    for (int L = 22; L >= 20; L--) {
        if (((size_t)8 << L) <= avail) { log_sz = L; break; }
    }

    // Zero the dense output (runtime fill hits ~6.3 TB/s in the timed graph;
    // a hand-rolled float4 zero kernel measured slower — round 3 post-mortem).
    hipMemsetAsync(d_out, 0, (size_t)out_size * sizeof(float), stream);

    node_proj_kernel<<<N, 128, 0, stream>>>(embed, W1, b1, Pcat);

    const int eb = 256;
    const int eg = (E + eb - 1) / eb;

    if (log_sz >= 20) {
        uint32_t* tab = (uint32_t*)((char*)d_ws + pcat_bytes);
        hipMemsetAsync(tab, 0, (size_t)8 << log_sz, stream);
        scatter_hash_kernel<<<eg, eb, 0, stream>>>(ei, Pcat, W2, b2, tab, E, N, log_sz);
        finalize_hash_kernel<<<eg, eb, 0, stream>>>(ei, tab, out, E, N, log_sz);
    } else {
        float* vals = (float*)((char*)d_ws + pcat_bytes);  // E floats
        edge_scatter_kernel<<<eg, eb, 0, stream>>>(ei, Pcat, W2, b2, out, E, N);
        edge_read_kernel<<<eg, eb, 0, stream>>>(ei, out, vals, E, N);
        edge_write_kernel<<<eg, eb, 0, stream>>>(ei, vals, out, E, N);
    }
}

// Round 6
// 219.529 us; speedup vs baseline: 1.0913x; 1.0913x over previous
//
#include <hip/hip_runtime.h>
#include <stdint.h>

#define D_EMB 128
#define HIDDEN 64
#define PACK_SCALE 1024.0f
#define INV_PACK (1.0f/1024.0f)
#define NODES_PER_BLK 8

__device__ __forceinline__ uint32_t rotl32(uint32_t x, int r) {
    return (x << r) | (x >> (32 - r));
}

// Bit-exact JAX threefry2x32, PARTITIONABLE path (default since jax 0.4.36).
// key = jax.random.key(42) -> (k1,k2) = (0,42); draw = final_x0 ^ final_x1 of
// counts (0, e).
__device__ __forceinline__ uint32_t jax_threefry_bits_part(uint32_t e) {
    const uint32_t ks0 = 0u;
    const uint32_t ks1 = 42u;
    const uint32_t ks2 = 0x1BD11BDAu ^ 0u ^ 42u;
    uint32_t x0 = 0u + ks0;
    uint32_t x1 = e + ks1;
#define TF_R(r) { x0 += x1; x1 = rotl32(x1, (r)); x1 ^= x0; }
    TF_R(13) TF_R(15) TF_R(26) TF_R(6)
    x0 += ks1; x1 += ks2 + 1u;
    TF_R(17) TF_R(29) TF_R(16) TF_R(24)
    x0 += ks2; x1 += ks0 + 2u;
    TF_R(13) TF_R(15) TF_R(26) TF_R(6)
    x0 += ks0; x1 += ks1 + 3u;
    TF_R(17) TF_R(29) TF_R(16) TF_R(24)
    x0 += ks1; x1 += ks2 + 4u;
    TF_R(13) TF_R(15) TF_R(26) TF_R(6)
    x0 += ks2; x1 += ks0 + 5u;
#undef TF_R
    return x0 ^ x1;
}

// Per-edge MLP logit -> concrete-sample gate value v in (0,1).
__device__ __forceinline__ float edge_gate_value(
    const float* __restrict__ Pcat, const float* __restrict__ w2s, float b2v,
    int c, int r, int e) {
    const float4* p1 = (const float4*)(Pcat + (size_t)c * (2 * HIDDEN));
    const float4* p2 = (const float4*)(Pcat + (size_t)r * (2 * HIDDEN) + HIDDEN);
    const float4* w4 = (const float4*)w2s;
    float la = b2v;
#pragma unroll
    for (int k = 0; k < HIDDEN / 4; k++) {
        float4 a = p1[k];
        float4 b = p2[k];
        float4 w = w4[k];
        la += fmaxf(a.x + b.x, 0.0f) * w.x + fmaxf(a.y + b.y, 0.0f) * w.y +
              fmaxf(a.z + b.z, 0.0f) * w.z + fmaxf(a.w + b.w, 0.0f) * w.w;
    }
    uint32_t bits = jax_threefry_bits_part((uint32_t)e);
    float u = __uint_as_float((bits >> 9) | 0x3f800000u) - 1.0f;
    // sigmoid(log(u) - log1p(-u) + la) == u / (u + (1-u)*exp(-la))
    return u / (u + (1.0f - u) * __expf(-la));
}

// Kernel 1: per-node projections, 8 nodes per block (8x less W1 L2 traffic).
// Pcat[n][0:64] = embed[n] @ W1[:128] + b1 ; Pcat[n][64:128] = embed[n] @ W1[128:]
__global__ __launch_bounds__(256) void node_proj_kernel(
    const float* __restrict__ embed, const float* __restrict__ W1,
    const float* __restrict__ b1, float* __restrict__ Pcat, int N) {
    __shared__ float e_lds[NODES_PER_BLK][D_EMB];
    int n0 = blockIdx.x * NODES_PER_BLK;
    int t = threadIdx.x;
    {   // cooperative float4 load: 8 nodes * 32 float4 = 256 float4 = 256 threads
        int node = n0 + (t >> 5);
        float4 v = make_float4(0.f, 0.f, 0.f, 0.f);
        if (node < N) v = ((const float4*)embed)[(size_t)n0 * (D_EMB / 4) + t];
        ((float4*)&e_lds[0][0])[t] = v;
    }
    __syncthreads();
#pragma unroll
    for (int rep = 0; rep < 4; rep++) {
        int idx = rep * 256 + t;               // 0..1023 = 8 nodes x 128 cols
        int nl = idx >> 7;
        int col = idx & 127;
        int half = col >> 6, k = col & 63;
        const float* w = W1 + (size_t)half * D_EMB * HIDDEN + k;
        float acc = (half == 0) ? b1[k] : 0.0f;
        const float* ev = e_lds[nl];
#pragma unroll 16
        for (int d = 0; d < D_EMB; d++) acc += ev[d] * w[(size_t)d * HIDDEN];
        if (n0 + nl < N) Pcat[(size_t)(n0 + nl) * (2 * HIDDEN) + col] = acc;
    }
}

// Kernel 2: per-edge gate value, packed atomic accumulate into out[c*N+r].
// Cell state after this pass: 1024*cnt + sum(v), always >= 1024 for touched.
__global__ __launch_bounds__(256) void edge_scatter_kernel(
    const int* __restrict__ ei, const float* __restrict__ Pcat,
    const float* __restrict__ W2, const float* __restrict__ b2,
    float* __restrict__ out, int E, int N) {
    __shared__ float w2s[HIDDEN];
    if (threadIdx.x < HIDDEN) w2s[threadIdx.x] = W2[threadIdx.x];
    __syncthreads();
    int e = blockIdx.x * blockDim.x + threadIdx.x;
    if (e >= E) return;
    int c = ei[e];
    int r = ei[E + e];
    if ((unsigned)c >= (unsigned)N || (unsigned)r >= (unsigned)N) return;
    float v = edge_gate_value(Pcat, w2s, b2[0], c, r, e);
    atomicAdd(out + (size_t)c * N + r, PACK_SCALE + v);
}

// Kernel 3: single-pass self-synchronizing symmetric finalize.
// States are disjoint: 0 = untouched, (0,1024) = finalized, >=1024 = packed.
// Owner (c<=r, or c>r with untouched mirror) writes BOTH cells' finals.
// All races are idempotent: finals are a deterministic function of the unique
// packed state, so any interleaving (incl. stale cross-XCD reads of the older
// packed state) produces identical bits.
__global__ __launch_bounds__(256) void edge_finalize_kernel(
    const int* __restrict__ ei, float* __restrict__ out, int E, int N) {
    int e = blockIdx.x * blockDim.x + threadIdx.x;
    if (e >= E) return;
    int c = ei[e];
    int r = ei[E + e];
    if ((unsigned)c >= (unsigned)N || (unsigned)r >= (unsigned)N) return;

    size_t own = (size_t)c * N + r;
    size_t mir = (size_t)r * N + c;
    float a = out[own];
    if (a < PACK_SCALE) return;            // duplicate already finalized own cell
    float b = out[mir];
    if (c != r && b > 0.0f && b < PACK_SCALE) return;  // pair mid-finalize by owner

    if (c <= r || b == 0.0f) {             // owner
        float cnt_a = truncf(a * INV_PACK);
        float s_a = a - PACK_SCALE * cnt_a;
        float cnt_b = truncf(b * INV_PACK); // b==0 -> 0,0
        float s_b = b - PACK_SCALE * cnt_b;
        float sum = s_a + s_b;             // c==r: a==b so sum = 2*s_a, correct
        out[own] = cnt_a * 0.5f * sum;
        if (c < r && b != 0.0f) out[mir] = cnt_b * 0.5f * sum;
    }
    // c>r with packed mirror: the mirror edge's owner thread writes both cells.
}

extern "C" void kernel_launch(void* const* d_in, const int* in_sizes, int n_in,
                              void* d_out, int out_size, void* d_ws, size_t ws_size,
                              hipStream_t stream) {
    const float* embed = (const float*)d_in[0];
    const int*   ei    = (const int*)d_in[1];
    const float* W1    = (const float*)d_in[2];
    const float* b1    = (const float*)d_in[3];
    const float* W2    = (const float*)d_in[4];
    const float* b2    = (const float*)d_in[5];
    float* out = (float*)d_out;

    const int N = in_sizes[0] / D_EMB;      // 10000
    const int E = in_sizes[1] / 2;          // 640000

    float* Pcat = (float*)d_ws;             // N*128 floats = 5.12 MB

    // Zero the dense output (in-graph memset; hand-rolled float4 zero kernel
    // measured slower — round 3 post-mortem).
    hipMemsetAsync(d_out, 0, (size_t)out_size * sizeof(float), stream);

    node_proj_kernel<<<(N + NODES_PER_BLK - 1) / NODES_PER_BLK, 256, 0, stream>>>(
        embed, W1, b1, Pcat, N);

    const int eb = 256;
    const int eg = (E + eb - 1) / eb;
    edge_scatter_kernel<<<eg, eb, 0, stream>>>(ei, Pcat, W2, b2, out, E, N);
    edge_finalize_kernel<<<eg, eb, 0, stream>>>(ei, out, E, N);
}